// Round 5
// baseline (2591.163 us; speedup 1.0000x reference)
//
#include <hip/hip_runtime.h>
#include <hip/hip_bf16.h>

#define T_STEPS 64
#define B_DIM 2048
#define U_DIM 1024
#define KITERS 32   // K-steps of 32 over U=1024

typedef __attribute__((ext_vector_type(8))) _Float16 h8;
typedef __attribute__((ext_vector_type(4))) float f4;

#define WAIT_VM0 __builtin_amdgcn_s_waitcnt(0x0F70)   // vmcnt(0)

__device__ __forceinline__ void async_cp16(const _Float16* g, _Float16* l) {
    __builtin_amdgcn_global_load_lds((const __attribute__((address_space(1))) void*)g,
                                     (__attribute__((address_space(3))) void*)l,
                                     16, 0, 0);
}

// ---------------- init kernels ----------------

// R: [U][2U] f32 row-major -> Rt: [2U][U] f16 (B^T layout)
__global__ void transpose_R(const float* __restrict__ R, _Float16* __restrict__ Rt) {
    __shared__ float tile[32][33];
    int nb = blockIdx.x * 32;
    int kb = blockIdx.y * 32;
    int tx = threadIdx.x, ty = threadIdx.y;   // block (32,8)
    #pragma unroll
    for (int i = ty; i < 32; i += 8)
        tile[i][tx] = R[(size_t)(kb + i) * (2 * U_DIM) + nb + tx];
    __syncthreads();
    #pragma unroll
    for (int i = ty; i < 32; i += 8)
        Rt[(size_t)(nb + i) * U_DIM + kb + tx] = (_Float16)tile[tx][i];
}

__global__ void init_state(const float* __restrict__ c0, _Float16* __restrict__ h0,
                           float* __restrict__ y, unsigned* __restrict__ bar) {
    int i = blockIdx.x * 256 + threadIdx.x;
    h0[i] = (_Float16)c0[i];
    if (i < 3 * B_DIM) y[i] = 0.f;
    if (i < 256) bar[i] = 0u;
}

// A-fragment direct-to-register load THROUGH L1 (no sc0): the ns-pair wave
// reads the same rows, so L1 serves the duplicate. Coherence with other CUs'
// c stores is restored by an L1-only buffer_inv after each chunk barrier.
#define ALOAD1(dst, addr, OFFSTR) \
    asm volatile("global_load_dwordx4 %0, %1, off offset:" OFFSTR \
                 : "=&v"(dst) : "v"(addr) : "memory")

#define ALOADG(S, OFFSTR) do { \
    ALOAD1(afq[S][0], am[0], OFFSTR); \
    ALOAD1(afq[S][1], am[1], OFFSTR); \
    ALOAD1(afq[S][2], am[2], OFFSTR); \
    ALOAD1(afq[S][3], am[3], OFFSTR); } while (0)

#define MFMA8(S) do { \
    __builtin_amdgcn_s_setprio(1); \
    _Pragma("unroll") \
    for (int mt = 0; mt < 4; ++mt) { \
        accF[mt] = __builtin_amdgcn_mfma_f32_16x16x32_f16(afq[S][mt], bff, accF[mt], 0, 0, 0); \
        accC[mt] = __builtin_amdgcn_mfma_f32_16x16x32_f16(afq[S][mt], bfc, accC[mt], 0, 0, 0); \
    } \
    __builtin_amdgcn_s_setprio(0); } while (0)

// steady-state: 4 groups x 4 loads outstanding -> wait oldest group: vmcnt(12)
#define KSTEP(KT, S, PFOFF) do { \
    h8 bff = *(const h8*)&lB[0][ns][KT][lane8]; \
    h8 bfc = *(const h8*)&lB[1][ns][KT][lane8]; \
    __builtin_amdgcn_s_waitcnt(0x0F7C); \
    __builtin_amdgcn_sched_barrier(0); \
    MFMA8(S); \
    ALOADG(S, PFOFF); } while (0)

#define KTAIL(KT, S, WENC) do { \
    h8 bff = *(const h8*)&lB[0][ns][KT][lane8]; \
    h8 bfc = *(const h8*)&lB[1][ns][KT][lane8]; \
    __builtin_amdgcn_s_waitcnt(WENC); \
    __builtin_amdgcn_sched_barrier(0); \
    MFMA8(S); } while (0)

// ---------------- persistent fused kernel ----------------
// Grid 256 = 32 u-chunks x 8 b-chunks, 1 block/CU, 512 threads = 8 waves
// = 4 row-groups (64 rows, mt=4) x 2 col-halves (ns, 16 u). Per kt a wave
// reads only 2 B-frags (vs 4) -> half the LDS traffic of R4; B staged in
// READ-ORDER (slot ℓ = lane ℓ's fragment) -> stride-16B conflict-free b128.
// B panel LDS-resident; A streams L2/L1->registers; per-chunk 32-block barrier.
__global__ __launch_bounds__(512, 2) void persist(
    _Float16* __restrict__ h0, _Float16* __restrict__ h1,
    const _Float16* __restrict__ Rt,
    const float* __restrict__ x1_0, const float* __restrict__ x2_0,
    const float* __restrict__ kern, const float* __restrict__ bias,
    const float* __restrict__ okern,
    float* y,                         // [3][B]  (agent-scope atomics only)
    const float* __restrict__ inputs, // [T][B]
    float* __restrict__ out,          // [T][B]
    unsigned* bar)                    // 8 groups x 32-uint padded lines
{
    // 128 KB persistent B: [gate][ns][kt][64 slots x 8 halfs], read-order
    __shared__ __align__(16) _Float16 lB[2][2][KITERS][512];
    __shared__ __align__(16) _Float16 lC[256 * 40];   // 20 KB epilogue staging
    __shared__ float x1s[256];                        // 1 KB

    const int tid    = threadIdx.x;
    const int wid    = tid >> 6;       // 0..7
    const int lane   = tid & 63;
    const int lane15 = lane & 15;
    const int quad   = lane >> 4;
    const int lane8  = lane * 8;       // read-order frag slot (halfs)
    const int bid    = blockIdx.x;
    const int b0     = (bid & 7) * 256;
    const int u0     = (bid >> 3) * 32;
    const bool ub0   = (bid >> 3) == 0;
    const int ms     = wid >> 1;       // row-group 0..3
    const int ns     = wid & 1;        // col-half 0..1
    const int wrow   = ms * 64;        // wave's 64 A-rows
    const int myb    = b0 + tid;       // valid for tid < 256
    unsigned* ctr   = &bar[(bid & 7) * 32];
    unsigned* xmask = &bar[(bid & 7) * 32 + 8];

    // ---- issue persistent-B DMAs, read-order scatter (128 x 1KB, 16/wave) ----
    // slot ℓ of region (g,nsr,kt) holds Rt[g*U + u0 + nsr*16 + (ℓ&15)][kt*32 + (ℓ>>4)*8]
    #pragma unroll
    for (int g = 0; g < 2; ++g)
        #pragma unroll
        for (int nsr = 0; nsr < 2; ++nsr)
            #pragma unroll
            for (int i = 0; i < 4; ++i) {
                const int kt = wid + i * 8;
                async_cp16(Rt + (size_t)(g * U_DIM + u0 + nsr * 16 + lane15) * U_DIM
                              + kt * 32 + quad * 8,
                           &lB[g][nsr][kt][0]);
            }

    // ---- XCD purity probe + first rendezvous (overlaps B DMA flight) ----
    int* flag = (int*)x1s;
    if (tid == 0) {
        const unsigned xcc = (unsigned)__builtin_amdgcn_s_getreg(63508) & 31u; // HW_REG_XCC_ID
        __hip_atomic_fetch_or(xmask, 1u << xcc, __ATOMIC_RELAXED, __HIP_MEMORY_SCOPE_AGENT);
        __hip_atomic_fetch_add(ctr, 1u, __ATOMIC_RELAXED, __HIP_MEMORY_SCOPE_AGENT);
        while (__hip_atomic_load(ctr, __ATOMIC_RELAXED, __HIP_MEMORY_SCOPE_AGENT) < 32u)
            __builtin_amdgcn_s_sleep(1);
        const unsigned m = __hip_atomic_load(xmask, __ATOMIC_RELAXED, __HIP_MEMORY_SCOPE_AGENT);
        *flag = (__popc(m) == 1) ? 1 : 0;
    }
    __syncthreads();
    const bool xcd_pure = (*flag != 0);

    // ---- loop-invariant epilogue constants (scalar: wave owns 16 u-cols) ----
    const int ucol = u0 + ns * 16 + lane15;
    const float kf  = kern[ucol];
    const float kc  = kern[U_DIM + ucol];
    const float bf_ = bias[ucol];
    const float bc_ = bias[U_DIM + ucol];
    const float ok_ = okern[ucol];

    // ---- h gate values: register-carried across ALL steps ----
    _Float16 hv[4][4];
    #pragma unroll
    for (int mt = 0; mt < 4; ++mt)
        #pragma unroll
        for (int reg = 0; reg < 4; ++reg)
            hv[mt][reg] = h0[(size_t)(b0 + wrow + mt * 16 + quad * 4 + reg) * U_DIM + ucol];

    float x1r = 0.f, x2r = 0.f;
    if (tid < 256) { x1r = x1_0[myb]; x2r = x2_0[myb]; }

    WAIT_VM0;            // B panel + hv resident
    __syncthreads();     // all waves' B visible; flag consumed

    _Float16* hA_ = h0;
    _Float16* hB_ = h1;

    #pragma unroll 1
    for (int t = 0; t < T_STEPS; ++t) {
        // ---- integrator update (y finalized by previous step's barrier) ----
        if (tid < 256) {
            if (t > 0) {
                const float ip = inputs[(size_t)(t - 1) * B_DIM + myb];
                const float yp = __hip_atomic_load(&y[((t + 2) % 3) * B_DIM + myb],
                                                   __ATOMIC_RELAXED, __HIP_MEMORY_SCOPE_AGENT);
                x1r = x1r + x2r;
                x2r = x2r + ip * yp;
            }
            if (ub0) {
                if (t > 0) out[(size_t)(t - 1) * B_DIM + myb] = x1r;
                if (t == T_STEPS - 1)
                    out[(size_t)(T_STEPS - 1) * B_DIM + myb] = x1r + x2r;  // x1_{T}
                else
                    __hip_atomic_store(&y[((t + 1) % 3) * B_DIM + myb], 0.f,
                                       __ATOMIC_RELAXED, __HIP_MEMORY_SCOPE_AGENT);
            }
            x1s[tid] = x1r;
        }
        if (t == T_STEPS - 1) break;   // step-63 GEMM output is never consumed

        __syncthreads();   // x1s visible for this step's epilogue

        // ---- A-fragment base addresses (per mt) ----
        unsigned long long am[4];
        {
            const _Float16* ab = hA_ + (size_t)(b0 + wrow + lane15) * U_DIM + quad * 8;
            #pragma unroll
            for (int mt = 0; mt < 4; ++mt)
                am[mt] = (unsigned long long)(ab + (size_t)mt * 16 * U_DIM);
        }

        f4 accF[4], accC[4];
        #pragma unroll
        for (int mt = 0; mt < 4; ++mt) {
            accF[mt] = (f4){0.f, 0.f, 0.f, 0.f};
            accC[mt] = (f4){0.f, 0.f, 0.f, 0.f};
        }

        // ---- K-loop: 4-deep register prefetch of A (4 loads/group) ----
        h8 afq[4][4];
        ALOADG(0, "0"); ALOADG(1, "64"); ALOADG(2, "128"); ALOADG(3, "192");
        KSTEP(0, 0, "256");   KSTEP(1, 1, "320");   KSTEP(2, 2, "384");   KSTEP(3, 3, "448");
        KSTEP(4, 0, "512");   KSTEP(5, 1, "576");   KSTEP(6, 2, "640");   KSTEP(7, 3, "704");
        KSTEP(8, 0, "768");   KSTEP(9, 1, "832");   KSTEP(10, 2, "896");  KSTEP(11, 3, "960");
        KSTEP(12, 0, "1024"); KSTEP(13, 1, "1088"); KSTEP(14, 2, "1152"); KSTEP(15, 3, "1216");
        KSTEP(16, 0, "1280"); KSTEP(17, 1, "1344"); KSTEP(18, 2, "1408"); KSTEP(19, 3, "1472");
        KSTEP(20, 0, "1536"); KSTEP(21, 1, "1600"); KSTEP(22, 2, "1664"); KSTEP(23, 3, "1728");
        KSTEP(24, 0, "1792"); KSTEP(25, 1, "1856"); KSTEP(26, 2, "1920"); KSTEP(27, 3, "1984");
        KTAIL(28, 0, 0x0F7C); KTAIL(29, 1, 0x0F78); KTAIL(30, 2, 0x0F74); KTAIL(31, 3, 0x0F70);

        // ---- epilogue: gates, c -> lC + hv register carry, y partials ----
        float* ycur = y + (t % 3) * B_DIM;
        const int ul = ns * 16 + lane15;
        #pragma unroll
        for (int mt = 0; mt < 4; ++mt) {
            const int rlb = wrow + mt * 16 + quad * 4;
            float psum[4];
            #pragma unroll
            for (int reg = 0; reg < 4; ++reg) {
                const int rl = rlb + reg;
                const float x1 = x1s[rl];
                const float xf = accF[mt][reg] + x1 * kf + bf_;
                const float xc = accC[mt][reg] + x1 * kc + bc_;
                const float fg = 1.f / (1.f + __expf(-xf));
                const float th = 1.f - 2.f / (1.f + __expf(2.f * xc));
                const float cv = fg * (float)hv[mt][reg] + (1.f - fg) * th;
                hv[mt][reg] = (_Float16)cv;       // gate value for step t+1
                lC[rl * 40 + ul] = (_Float16)cv;
                psum[reg] = cv * ok_;
            }
            #pragma unroll
            for (int reg = 0; reg < 4; ++reg) {
                float s = psum[reg];
                s += __shfl_xor(s, 1);
                s += __shfl_xor(s, 2);
                s += __shfl_xor(s, 4);
                s += __shfl_xor(s, 8);
                if (lane15 == 0) atomicAdd(&ycur[b0 + rlb + reg], s);
            }
        }

        // ---- coalesced c write-out ----
        __syncthreads();
        #pragma unroll
        for (int j = 0; j < 2; ++j) {
            const int idx = j * 512 + tid;       // 1024 uint4 = 256 rows x 4
            const int row = idx >> 2;
            const int col = idx & 3;
            *(uint4*)&hB_[(size_t)(b0 + row) * U_DIM + u0 + col * 8] =
                *(const uint4*)&lC[row * 40 + col * 8];
        }

        { _Float16* tmp = hA_; hA_ = hB_; hB_ = tmp; }

        // ---- per-chunk 32-block barrier (cumulative counter) ----
        if (!xcd_pure) __builtin_amdgcn_fence(__ATOMIC_RELEASE, "agent");
        __syncthreads();   // drains vmcnt(0): c stores at XCD L2
        if (tid == 0) {
            __hip_atomic_fetch_add(ctr, 1u, __ATOMIC_RELAXED, __HIP_MEMORY_SCOPE_AGENT);
            while (__hip_atomic_load(ctr, __ATOMIC_RELAXED, __HIP_MEMORY_SCOPE_AGENT)
                   < 32u * (unsigned)(t + 2))            // +32 startup rendezvous
                __builtin_amdgcn_s_sleep(1);
        }
        __syncthreads();
        if (xcd_pure) {
            // L1-only invalidate: next step's A loads must not hit stale L1
            // lines (same addresses recur every 2 steps). L2 stays intact.
            asm volatile("buffer_inv" ::: "memory");
        } else {
            __builtin_amdgcn_fence(__ATOMIC_ACQUIRE, "agent");   // L1+L2 inv
        }
    }
}

// ---------------- host ----------------
extern "C" void kernel_launch(void* const* d_in, const int* in_sizes, int n_in,
                              void* d_out, int out_size, void* d_ws, size_t ws_size,
                              hipStream_t stream) {
    const float* inputs = (const float*)d_in[0];
    const float* x1_0   = (const float*)d_in[1];
    const float* x2_0   = (const float*)d_in[2];
    const float* c0     = (const float*)d_in[3];
    const float* kern   = (const float*)d_in[4];
    const float* rker   = (const float*)d_in[5];
    const float* bias   = (const float*)d_in[6];
    const float* okern  = (const float*)d_in[7];
    float* out = (float*)d_out;

    _Float16* Rt = (_Float16*)d_ws;                       // 4 MB
    _Float16* h0 = Rt + (size_t)2 * U_DIM * U_DIM;        // 4 MB
    _Float16* h1 = h0 + (size_t)B_DIM * U_DIM;            // 4 MB
    float* y = (float*)(h1 + (size_t)B_DIM * U_DIM);      // 3*B
    unsigned* bar = (unsigned*)(y + 3 * B_DIM);           // 256 uints

    transpose_R<<<dim3(64, 32), dim3(32, 8), 0, stream>>>(rker, Rt);
    init_state<<<dim3(B_DIM * U_DIM / 256), dim3(256), 0, stream>>>(c0, h0, y, bar);
    persist<<<dim3(256), dim3(512), 0, stream>>>(h0, h1, Rt, x1_0, x2_0,
                                                 kern, bias, okern, y, inputs, out, bar);
}

// Round 6
// 1420.756 us; speedup vs baseline: 1.8238x; 1.8238x over previous
//
#include <hip/hip_runtime.h>
#include <hip/hip_bf16.h>

#define T_STEPS 64
#define B_DIM 2048
#define U_DIM 1024
#define KITERS 32   // K-steps of 32 over U=1024

typedef __attribute__((ext_vector_type(8))) _Float16 h8;
typedef __attribute__((ext_vector_type(4))) float f4;

#define WAIT_VM0 __builtin_amdgcn_s_waitcnt(0x0F70)   // vmcnt(0)

__device__ __forceinline__ void async_cp16(const _Float16* g, _Float16* l) {
    __builtin_amdgcn_global_load_lds((const __attribute__((address_space(1))) void*)g,
                                     (__attribute__((address_space(3))) void*)l,
                                     16, 0, 0);
}

// ---------------- init kernels ----------------

// R: [U][2U] f32 row-major -> Rt: [2U][U] f16 (B^T layout)
__global__ void transpose_R(const float* __restrict__ R, _Float16* __restrict__ Rt) {
    __shared__ float tile[32][33];
    int nb = blockIdx.x * 32;
    int kb = blockIdx.y * 32;
    int tx = threadIdx.x, ty = threadIdx.y;   // block (32,8)
    #pragma unroll
    for (int i = ty; i < 32; i += 8)
        tile[i][tx] = R[(size_t)(kb + i) * (2 * U_DIM) + nb + tx];
    __syncthreads();
    #pragma unroll
    for (int i = ty; i < 32; i += 8)
        Rt[(size_t)(nb + i) * U_DIM + kb + tx] = (_Float16)tile[tx][i];
}

__global__ void init_state(const float* __restrict__ c0, _Float16* __restrict__ h0,
                           float* __restrict__ y, unsigned* __restrict__ bar) {
    int i = blockIdx.x * 256 + threadIdx.x;
    h0[i] = (_Float16)c0[i];
    if (i < 3 * B_DIM) y[i] = 0.f;
    if (i < 256) bar[i] = 0u;
}

// A-fragment direct-to-register load, L1-bypass (sc0): served by the
// XCD-coherent L2 (proven R2-R4). Addresses runtime-computed (K-rotation).
#define ALOADG(S, KQ) do { \
    const _Float16* a0_ = am0 + (KQ) * 32; \
    const _Float16* a1_ = am1 + (KQ) * 32; \
    asm volatile("global_load_dwordx4 %0, %2, off sc0\n\t" \
                 "global_load_dwordx4 %1, %3, off sc0" \
                 : "=&v"(afq[S][0]), "=&v"(afq[S][1]) \
                 : "v"(a0_), "v"(a1_) : "memory"); } while (0)

#define MFMA8(S) do { \
    __builtin_amdgcn_s_setprio(1); \
    _Pragma("unroll") \
    for (int mt = 0; mt < 2; ++mt) { \
        accF[mt][0] = __builtin_amdgcn_mfma_f32_16x16x32_f16(afq[S][mt], bff0, accF[mt][0], 0, 0, 0); \
        accF[mt][1] = __builtin_amdgcn_mfma_f32_16x16x32_f16(afq[S][mt], bff1, accF[mt][1], 0, 0, 0); \
        accC[mt][0] = __builtin_amdgcn_mfma_f32_16x16x32_f16(afq[S][mt], bfc0, accC[mt][0], 0, 0, 0); \
        accC[mt][1] = __builtin_amdgcn_mfma_f32_16x16x32_f16(afq[S][mt], bfc1, accC[mt][1], 0, 0, 0); \
    } \
    __builtin_amdgcn_s_setprio(0); } while (0)

// steady-state: 4 groups x 2 loads outstanding -> wait oldest group: vmcnt(6)
#define KSTEP(G, S) do { \
    const int ktp_ = (rot + (G)) & 31; \
    h8 bff0 = *(const h8*)&lB[0][0][ktp_][lane8]; \
    h8 bff1 = *(const h8*)&lB[0][1][ktp_][lane8]; \
    h8 bfc0 = *(const h8*)&lB[1][0][ktp_][lane8]; \
    h8 bfc1 = *(const h8*)&lB[1][1][ktp_][lane8]; \
    __builtin_amdgcn_s_waitcnt(0x0F76); \
    __builtin_amdgcn_sched_barrier(0); \
    MFMA8(S); \
    ALOADG(S, (rot + (G) + 4) & 31); } while (0)

#define KTAIL(G, S, WENC) do { \
    const int ktp_ = (rot + (G)) & 31; \
    h8 bff0 = *(const h8*)&lB[0][0][ktp_][lane8]; \
    h8 bff1 = *(const h8*)&lB[0][1][ktp_][lane8]; \
    h8 bfc0 = *(const h8*)&lB[1][0][ktp_][lane8]; \
    h8 bfc1 = *(const h8*)&lB[1][1][ktp_][lane8]; \
    __builtin_amdgcn_s_waitcnt(WENC); \
    __builtin_amdgcn_sched_barrier(0); \
    MFMA8(S); } while (0)

// ---------------- persistent fused kernel ----------------
// Grid 256 = 32 u-chunks x 8 b-chunks, 1 block/CU, 512 threads = 8 waves
// (each wave: 32 A-rows, both 16-col halves -> A read exactly once per CU).
// B panel LDS-resident in READ-ORDER layout (slot = reading lane) ->
// conflict-free b128 reads (proven R5: conflicts 6.8e7 -> 2.1e6).
// K-ROTATION: u-block ub visits K-tiles (ub+g)&31 so the 32 blocks of a
// chunk touch 32 DIFFERENT A K-tiles at any instant -> L2 bank despread
// (attacks the R4 TLP-null = L2-hotspot diagnosis).
__global__ __launch_bounds__(512, 2) void persist(
    _Float16* __restrict__ h0, _Float16* __restrict__ h1,
    const _Float16* __restrict__ Rt,
    const float* __restrict__ x1_0, const float* __restrict__ x2_0,
    const float* __restrict__ kern, const float* __restrict__ bias,
    const float* __restrict__ okern,
    float* y,                         // [3][B]  (agent-scope atomics only)
    const float* __restrict__ inputs, // [T][B]
    float* __restrict__ out,          // [T][B]
    unsigned* bar)                    // 8 groups x 32-uint padded lines
{
    // 128 KB persistent B: [gate][nt][kt][64 slots x 8 halfs], read-order
    __shared__ __align__(16) _Float16 lB[2][2][KITERS][512];
    __shared__ __align__(16) _Float16 lC[256 * 40];   // 20 KB epilogue staging
    __shared__ float x1s[256];                        // 1 KB

    const int tid    = threadIdx.x;
    const int wid    = tid >> 6;       // 0..7
    const int lane   = tid & 63;
    const int lane15 = lane & 15;
    const int quad   = lane >> 4;
    const int lane8  = lane * 8;       // read-order frag slot (halfs)
    const int bid    = blockIdx.x;
    const int b0     = (bid & 7) * 256;
    const int u0     = (bid >> 3) * 32;
    const int rot    = bid >> 3;       // K-rotation = u-block id (0..31)
    const bool ub0   = (bid >> 3) == 0;
    const int wrow   = wid * 32;       // wave's 32 A-rows
    const int myb    = b0 + tid;       // valid for tid < 256
    unsigned* ctr   = &bar[(bid & 7) * 32];
    unsigned* xmask = &bar[(bid & 7) * 32 + 8];

    // ---- issue persistent-B DMAs, read-order scatter (128 x 1KB, 16/wave) ----
    // slot ℓ of region (g,nt,kt) holds Rt[g*U + u0 + nt*16 + (ℓ&15)][kt*32 + (ℓ>>4)*8]
    #pragma unroll
    for (int g = 0; g < 2; ++g)
        #pragma unroll
        for (int nt = 0; nt < 2; ++nt)
            #pragma unroll
            for (int i = 0; i < 4; ++i) {
                const int kt = wid + i * 8;
                async_cp16(Rt + (size_t)(g * U_DIM + u0 + nt * 16 + lane15) * U_DIM
                              + kt * 32 + quad * 8,
                           &lB[g][nt][kt][0]);
            }

    // ---- XCD purity probe + first rendezvous (overlaps B DMA flight) ----
    int* flag = (int*)x1s;
    if (tid == 0) {
        const unsigned xcc = (unsigned)__builtin_amdgcn_s_getreg(63508) & 31u; // HW_REG_XCC_ID
        __hip_atomic_fetch_or(xmask, 1u << xcc, __ATOMIC_RELAXED, __HIP_MEMORY_SCOPE_AGENT);
        __hip_atomic_fetch_add(ctr, 1u, __ATOMIC_RELAXED, __HIP_MEMORY_SCOPE_AGENT);
        while (__hip_atomic_load(ctr, __ATOMIC_RELAXED, __HIP_MEMORY_SCOPE_AGENT) < 32u)
            __builtin_amdgcn_s_sleep(1);
        const unsigned m = __hip_atomic_load(xmask, __ATOMIC_RELAXED, __HIP_MEMORY_SCOPE_AGENT);
        *flag = (__popc(m) == 1) ? 1 : 0;
    }
    __syncthreads();
    const bool xcd_pure = (*flag != 0);

    // ---- loop-invariant epilogue constants ----
    float kf[2], kc[2], bf_[2], bc_[2], ok_[2];
    #pragma unroll
    for (int nt = 0; nt < 2; ++nt) {
        const int u = u0 + nt * 16 + lane15;
        kf[nt]  = kern[u];        kc[nt]  = kern[U_DIM + u];
        bf_[nt] = bias[u];        bc_[nt] = bias[U_DIM + u];
        ok_[nt] = okern[u];
    }

    // ---- h gate values: register-carried across ALL steps ----
    _Float16 hv[2][2][4];
    #pragma unroll
    for (int mt = 0; mt < 2; ++mt)
        #pragma unroll
        for (int nt = 0; nt < 2; ++nt)
            #pragma unroll
            for (int reg = 0; reg < 4; ++reg)
                hv[mt][nt][reg] = h0[(size_t)(b0 + wrow + mt * 16 + quad * 4 + reg) * U_DIM
                                     + u0 + nt * 16 + lane15];

    float x1r = 0.f, x2r = 0.f;
    if (tid < 256) { x1r = x1_0[myb]; x2r = x2_0[myb]; }

    WAIT_VM0;            // B panel + hv resident
    __syncthreads();     // all waves' B visible; flag consumed

    _Float16* hA_ = h0;
    _Float16* hB_ = h1;

    #pragma unroll 1
    for (int t = 0; t < T_STEPS; ++t) {
        // ---- integrator update (y finalized by previous step's barrier) ----
        if (tid < 256) {
            if (t > 0) {
                const float ip = inputs[(size_t)(t - 1) * B_DIM + myb];
                const float yp = __hip_atomic_load(&y[((t + 2) % 3) * B_DIM + myb],
                                                   __ATOMIC_RELAXED, __HIP_MEMORY_SCOPE_AGENT);
                x1r = x1r + x2r;
                x2r = x2r + ip * yp;
            }
            if (ub0) {
                if (t > 0) out[(size_t)(t - 1) * B_DIM + myb] = x1r;
                if (t == T_STEPS - 1)
                    out[(size_t)(T_STEPS - 1) * B_DIM + myb] = x1r + x2r;  // x1_{T}
                else
                    __hip_atomic_store(&y[((t + 1) % 3) * B_DIM + myb], 0.f,
                                       __ATOMIC_RELAXED, __HIP_MEMORY_SCOPE_AGENT);
            }
            x1s[tid] = x1r;
        }
        if (t == T_STEPS - 1) break;   // step-63 GEMM output is never consumed

        __syncthreads();   // x1s visible for this step's epilogue

        // ---- A-fragment row bases (K offset applied per group) ----
        const _Float16* am0 = hA_ + (size_t)(b0 + wrow + lane15) * U_DIM + quad * 8;
        const _Float16* am1 = am0 + (size_t)16 * U_DIM;

        f4 accF[2][2], accC[2][2];
        #pragma unroll
        for (int mt = 0; mt < 2; ++mt)
            #pragma unroll
            for (int nt = 0; nt < 2; ++nt) {
                accF[mt][nt] = (f4){0.f, 0.f, 0.f, 0.f};
                accC[mt][nt] = (f4){0.f, 0.f, 0.f, 0.f};
            }

        // ---- K-loop: 4-deep prefetch, rotated K order (L2 despread) ----
        h8 afq[4][2];
        ALOADG(0, rot);
        ALOADG(1, (rot + 1) & 31);
        ALOADG(2, (rot + 2) & 31);
        ALOADG(3, (rot + 3) & 31);
        KSTEP(0, 0);  KSTEP(1, 1);  KSTEP(2, 2);  KSTEP(3, 3);
        KSTEP(4, 0);  KSTEP(5, 1);  KSTEP(6, 2);  KSTEP(7, 3);
        KSTEP(8, 0);  KSTEP(9, 1);  KSTEP(10, 2); KSTEP(11, 3);
        KSTEP(12, 0); KSTEP(13, 1); KSTEP(14, 2); KSTEP(15, 3);
        KSTEP(16, 0); KSTEP(17, 1); KSTEP(18, 2); KSTEP(19, 3);
        KSTEP(20, 0); KSTEP(21, 1); KSTEP(22, 2); KSTEP(23, 3);
        KSTEP(24, 0); KSTEP(25, 1); KSTEP(26, 2); KSTEP(27, 3);
        KTAIL(28, 0, 0x0F76); KTAIL(29, 1, 0x0F74); KTAIL(30, 2, 0x0F72); KTAIL(31, 3, 0x0F70);

        // ---- epilogue: gates, c -> lC + hv register carry, y partials ----
        float* ycur = y + (t % 3) * B_DIM;
        #pragma unroll
        for (int mt = 0; mt < 2; ++mt) {
            const int rlb = wrow + mt * 16 + quad * 4;
            float psum[4] = {0.f, 0.f, 0.f, 0.f};
            #pragma unroll
            for (int nt = 0; nt < 2; ++nt) {
                const int ul = nt * 16 + lane15;
                #pragma unroll
                for (int reg = 0; reg < 4; ++reg) {
                    const int rl = rlb + reg;
                    const float x1 = x1s[rl];
                    const float xf = accF[mt][nt][reg] + x1 * kf[nt] + bf_[nt];
                    const float xc = accC[mt][nt][reg] + x1 * kc[nt] + bc_[nt];
                    const float fg = 1.f / (1.f + __expf(-xf));
                    const float th = 1.f - 2.f / (1.f + __expf(2.f * xc));
                    const float cv = fg * (float)hv[mt][nt][reg] + (1.f - fg) * th;
                    hv[mt][nt][reg] = (_Float16)cv;       // gate value for step t+1
                    lC[rl * 40 + ul] = (_Float16)cv;
                    psum[reg] += cv * ok_[nt];
                }
            }
            #pragma unroll
            for (int reg = 0; reg < 4; ++reg) {
                float s = psum[reg];
                s += __shfl_xor(s, 1);
                s += __shfl_xor(s, 2);
                s += __shfl_xor(s, 4);
                s += __shfl_xor(s, 8);
                if (lane15 == 0) atomicAdd(&ycur[b0 + rlb + reg], s);
            }
        }

        // ---- coalesced c write-out ----
        __syncthreads();
        #pragma unroll
        for (int j = 0; j < 2; ++j) {
            const int idx = j * 512 + tid;       // 1024 uint4 = 256 rows x 4
            const int row = idx >> 2;
            const int col = idx & 3;
            *(uint4*)&hB_[(size_t)(b0 + row) * U_DIM + u0 + col * 8] =
                *(const uint4*)&lC[row * 40 + col * 8];
        }

        { _Float16* tmp = hA_; hA_ = hB_; hB_ = tmp; }

        // ---- per-chunk 32-block barrier (cumulative counter) ----
        if (!xcd_pure) __builtin_amdgcn_fence(__ATOMIC_RELEASE, "agent");
        __syncthreads();   // drains vmcnt(0): c stores at XCD L2
        if (tid == 0) {
            __hip_atomic_fetch_add(ctr, 1u, __ATOMIC_RELAXED, __HIP_MEMORY_SCOPE_AGENT);
            while (__hip_atomic_load(ctr, __ATOMIC_RELAXED, __HIP_MEMORY_SCOPE_AGENT)
                   < 32u * (unsigned)(t + 2))            // +32 startup rendezvous
                __builtin_amdgcn_s_sleep(1);
        }
        __syncthreads();
        if (!xcd_pure) __builtin_amdgcn_fence(__ATOMIC_ACQUIRE, "agent");
    }
}

// ---------------- host ----------------
extern "C" void kernel_launch(void* const* d_in, const int* in_sizes, int n_in,
                              void* d_out, int out_size, void* d_ws, size_t ws_size,
                              hipStream_t stream) {
    const float* inputs = (const float*)d_in[0];
    const float* x1_0   = (const float*)d_in[1];
    const float* x2_0   = (const float*)d_in[2];
    const float* c0     = (const float*)d_in[3];
    const float* kern   = (const float*)d_in[4];
    const float* rker   = (const float*)d_in[5];
    const float* bias   = (const float*)d_in[6];
    const float* okern  = (const float*)d_in[7];
    float* out = (float*)d_out;

    _Float16* Rt = (_Float16*)d_ws;                       // 4 MB
    _Float16* h0 = Rt + (size_t)2 * U_DIM * U_DIM;        // 4 MB
    _Float16* h1 = h0 + (size_t)B_DIM * U_DIM;            // 4 MB
    float* y = (float*)(h1 + (size_t)B_DIM * U_DIM);      // 3*B
    unsigned* bar = (unsigned*)(y + 3 * B_DIM);           // 256 uints

    transpose_R<<<dim3(64, 32), dim3(32, 8), 0, stream>>>(rker, Rt);
    init_state<<<dim3(B_DIM * U_DIM / 256), dim3(256), 0, stream>>>(c0, h0, y, bar);
    persist<<<dim3(256), dim3(512), 0, stream>>>(h0, h1, Rt, x1_0, x2_0,
                                                 kern, bias, okern, y, inputs, out, bar);
}